// Round 1
// baseline (21.943 us; speedup 1.0000x reference)
//
#include <hip/hip_runtime.h>

// Problem constants (fixed by setup_inputs shapes)
#define HOUT 39
#define WOUT 39
#define COUT 64
#define HIN  160
#define WIN  160
#define CIN  4
#define F    8
#define S    4

// One wave (64 lanes) per output spatial position (i,j); lane = output channel c.
// Each lane scans the 256-element patch*weight product, tracks argmax with
// first-occurrence tie-breaking (strict >, ascending k), then atomically adds
// its relevance at the winning flat input index.
__global__ __launch_bounds__(256) void argmax_rel_kernel(
    const float* __restrict__ rel,   // [39,39,64] relevance
    const float* __restrict__ x,     // [160,160,4] analyzed layer input map
    const float* __restrict__ w,     // [8,8,4,64] -> flat [k=(px*8+py)*4+pc][c]
    float* __restrict__ out)         // [160,160,4], pre-zeroed
{
    const int wid = (blockIdx.x * blockDim.x + threadIdx.x) >> 6; // (i,j) index
    const int c   = threadIdx.x & 63;
    if (wid >= HOUT * WOUT) return;
    const int i = wid / WOUT;
    const int j = wid - i * WOUT;

    const float* xp = x + ((S * i) * WIN + (S * j)) * CIN;

    float m   = -__builtin_inff();
    int   arg = 0;
    int   k   = 0;
    #pragma unroll
    for (int px = 0; px < F; ++px) {
        const float* row = xp + px * (WIN * CIN);   // 32 contiguous floats
        #pragma unroll
        for (int t = 0; t < F * CIN; ++t) {
            const float pv = row[t];                 // wave-uniform -> broadcast
            const float wv = w[k * COUT + c];        // coalesced across lanes
            const float p  = pv * wv;
            if (p > m) { m = p; arg = k; }           // strict >: first-max wins
            ++k;
        }
    }

    // arg = (px*8 + py)*4 + pc ; global flat index into [160,160,4]
    const int px_  = arg >> 5;          // patch row
    const int rem  = arg & 31;          // py*4 + pc
    const int gx   = S * i + px_;
    const int flat = gx * (WIN * CIN) + (S * j) * CIN + rem; // ((gx*160)+gy)*4+pc

    const float r = rel[wid * COUT + c];
    atomicAdd(out + flat, r);
}

extern "C" void kernel_launch(void* const* d_in, const int* in_sizes, int n_in,
                              void* d_out, int out_size, void* d_ws, size_t ws_size,
                              hipStream_t stream) {
    const float* rel = (const float*)d_in[0];   // [1,39,39,64]
    const float* x   = (const float*)d_in[1];   // [1,160,160,4]
    const float* w   = (const float*)d_in[2];   // [8,8,4,64]
    // d_in[3] = stride(4), d_in[4] = filter_size(8) -- compile-time constants here
    float* out = (float*)d_out;                 // [1,160,160,4]

    // Output is scatter-add target: must start at zero every call.
    hipMemsetAsync(out, 0, (size_t)out_size * sizeof(float), stream);

    const int positions = HOUT * WOUT;          // 1521 waves
    const int waves_per_block = 4;              // 256 threads
    const int blocks = (positions + waves_per_block - 1) / waves_per_block; // 381
    argmax_rel_kernel<<<blocks, 256, 0, stream>>>(rel, x, w, out);
}

// Round 2
// 18.943 us; speedup vs baseline: 1.1584x; 1.1584x over previous
//
#include <hip/hip_runtime.h>

// Problem constants (fixed by setup_inputs shapes)
#define HOUT 39
#define WOUT 39
#define COUT 64
#define HIN  160
#define WIN  160
#define CIN  4
#define F    8
#define S    4

// Block = one output position (i,j); 4 waves split the 256-element patch
// (k = (px*8+py)*4+pc) into 4 contiguous segments of 64; lane = channel c.
// Each wave runs 4 independent 16-long argmax chains (ILP), merges them in
// ascending-k order with strict > (first-occurrence ties, like jnp.argmax),
// then waves merge via LDS and wave 0 scatters with atomicAdd.
__global__ __launch_bounds__(256) void argmax_rel_kernel(
    const float* __restrict__ rel,   // [39,39,64]
    const float* __restrict__ x,     // [160,160,4]
    const float* __restrict__ w,     // [8,8,4,64] flat: [k][c]
    float* __restrict__ out)         // [160,160,4], pre-zeroed
{
    const int ij = blockIdx.x;                  // 0..1520
    const int i  = ij / WOUT;
    const int j  = ij - i * WOUT;
    const int wv = threadIdx.x >> 6;            // wave 0..3 -> k in [wv*64, wv*64+64)
    const int c  = threadIdx.x & 63;

    const float* xp   = x + ((S * i) * WIN + (S * j)) * CIN;  // patch origin
    const int    kb   = wv * 64;                // covers patch rows px = 2wv, 2wv+1
    const float* row0 = xp + (2 * wv) * (WIN * CIN);          // 32 floats
    const float* row1 = row0 + WIN * CIN;                     // 32 floats
    const float* wp   = w + kb * COUT + c;      // this wave's weight column base

    float m0 = -__builtin_inff(), m1 = m0, m2 = m0, m3 = m0;
    int   a0 = 0, a1 = 16, a2 = 32, a3 = 48;

    #pragma unroll
    for (int t = 0; t < 16; ++t) {
        // x values are wave-uniform (HW broadcast); w loads coalesced over c.
        const float p0 = row0[t]      * wp[(t)      * COUT];
        const float p1 = row0[16 + t] * wp[(16 + t) * COUT];
        const float p2 = row1[t]      * wp[(32 + t) * COUT];
        const float p3 = row1[16 + t] * wp[(48 + t) * COUT];
        if (p0 > m0) { m0 = p0; a0 = t; }
        if (p1 > m1) { m1 = p1; a1 = 16 + t; }
        if (p2 > m2) { m2 = p2; a2 = 32 + t; }
        if (p3 > m3) { m3 = p3; a3 = 48 + t; }
    }

    // merge 4 chains, ascending k, strict > keeps earliest k on ties
    float m = m0; int a = a0;
    if (m1 > m) { m = m1; a = a1; }
    if (m2 > m) { m = m2; a = a2; }
    if (m3 > m) { m = m3; a = a3; }
    a += kb;                                    // global k in [0,256)

    __shared__ float lm[4][COUT];
    __shared__ int   la[4][COUT];
    lm[wv][c] = m;
    la[wv][c] = a;
    __syncthreads();

    if (wv == 0) {
        float bm = lm[0][c]; int ba = la[0][c];
        #pragma unroll
        for (int s = 1; s < 4; ++s) {
            const float sm = lm[s][c];
            if (sm > bm) { bm = sm; ba = la[s][c]; }
        }
        // ba = (px*8+py)*4+pc ; flat output index
        const int px_  = ba >> 5;               // patch row
        const int rem  = ba & 31;               // py*4+pc
        const int gx   = S * i + px_;
        const int flat = gx * (WIN * CIN) + (S * j) * CIN + rem;

        atomicAdd(out + flat, rel[ij * COUT + c]);
    }
}

extern "C" void kernel_launch(void* const* d_in, const int* in_sizes, int n_in,
                              void* d_out, int out_size, void* d_ws, size_t ws_size,
                              hipStream_t stream) {
    const float* rel = (const float*)d_in[0];   // [1,39,39,64]
    const float* x   = (const float*)d_in[1];   // [1,160,160,4]
    const float* w   = (const float*)d_in[2];   // [8,8,4,64]
    float* out = (float*)d_out;                 // [1,160,160,4]

    hipMemsetAsync(out, 0, (size_t)out_size * sizeof(float), stream);

    argmax_rel_kernel<<<HOUT * WOUT, 256, 0, stream>>>(rel, x, w, out);
}